// Round 1
// baseline (641.096 us; speedup 1.0000x reference)
//
#include <hip/hip_runtime.h>
#include <cstddef>

#define NN 8192
#define CC 128

// ---------------- small utility kernels ----------------

__global__ __launch_bounds__(256) void fill_ones_k(float* p, int n) {
  int i = blockIdx.x * 256 + threadIdx.x;
  if (i < n) p[i] = 1.0f;
}

__global__ __launch_bounds__(256) void count_deg_k(const int* __restrict__ dst, float* deg, int E) {
  int i = blockIdx.x * 256 + threadIdx.x;
  if (i < E) atomicAdd(&deg[dst[i]], 1.0f);
}

__global__ __launch_bounds__(256) void rsqrt_k(float* p, int n) {
  int i = blockIdx.x * 256 + threadIdx.x;
  if (i < n) p[i] = rsqrtf(p[i]);  // deg >= 1 always (self loop), max(deg,1)==deg
}

__global__ __launch_bounds__(256) void scatter_k(const int* __restrict__ src, const int* __restrict__ dst,
    const float* __restrict__ xw, const float* __restrict__ dinv, float* __restrict__ hconv, int E) {
  int idx = blockIdx.x * 256 + threadIdx.x;
  int e = idx >> 5, c4 = idx & 31;
  if (e >= E) return;
  int s = src[e], d = dst[e];
  float coeff = dinv[s] * dinv[d];
  float4 v = *(const float4*)(xw + (size_t)s * CC + c4 * 4);
  float* o = hconv + (size_t)d * CC + c4 * 4;
  atomicAdd(o + 0, v.x * coeff);
  atomicAdd(o + 1, v.y * coeff);
  atomicAdd(o + 2, v.z * coeff);
  atomicAdd(o + 3, v.w * coeff);
}

// h = hconv + xw*dinv^2 (self loop) + conv_b + x  (pre-BN value of branch 1)
__global__ __launch_bounds__(256) void conv_finish_k(float* __restrict__ h, const float* __restrict__ xw,
    const float* __restrict__ dinv, const float* __restrict__ cb, const float* __restrict__ x) {
  int idx = blockIdx.x * 256 + threadIdx.x;
  int i = idx >> 7, c = idx & 127;
  float di = dinv[i];
  h[idx] = h[idx] + xw[idx] * di * di + cb[c] + x[idx];
}

__global__ __launch_bounds__(256) void bn_stats_k(const float* __restrict__ X,
    float* __restrict__ sums, float* __restrict__ sumsq) {
  int t = threadIdx.x;
  int c = t & 127, rg = t >> 7;
  int r0 = blockIdx.x * 64;
  float s = 0.f, sq = 0.f;
  for (int i = 0; i < 32; ++i) {
    float v = X[(size_t)(r0 + rg + 2 * i) * CC + c];
    s += v; sq += v * v;
  }
  atomicAdd(&sums[c], s);
  atomicAdd(&sumsq[c], sq);
}

__global__ void bn_finalize_k(const float* sums, const float* sumsq, const float* g, const float* be,
                              float* scale, float* shift) {
  int c = threadIdx.x;
  float mu = sums[c] * (1.0f / NN);
  float var = sumsq[c] * (1.0f / NN) - mu * mu;   // biased var, matches reference
  float sc = g[c] * rsqrtf(var + 1e-5f);
  scale[c] = sc;
  shift[c] = be[c] - mu * sc;
}

__global__ __launch_bounds__(256) void combine_k(const float* __restrict__ h1, const float* __restrict__ h2,
    const float* __restrict__ sc0, const float* __restrict__ sh0,
    const float* __restrict__ sc1, const float* __restrict__ sh1, float* __restrict__ out) {
  int idx = blockIdx.x * 256 + threadIdx.x;
  int c = idx & 127;
  out[idx] = sc0[c] * h1[idx] + sh0[c] + sc1[c] * h2[idx] + sh1[c];
}

__global__ __launch_bounds__(256) void bn_apply_k(const float* __restrict__ h, const float* __restrict__ sc,
    const float* __restrict__ sh, float* __restrict__ out) {
  int idx = blockIdx.x * 256 + threadIdx.x;
  int c = idx & 127;
  out[idx] = sc[c] * h[idx] + sh[c];
}

// ---------------- fp32 GEMM: out = (A@W + bias)*scale, optional relu, + resid ----------------
// grid (M/64, N/64), block 256. 64x64 tile, 4x4 register tile per thread.
__global__ __launch_bounds__(256) void gemm_k(const float* __restrict__ A, const float* __restrict__ W,
    const float* __restrict__ bias, const float* __restrict__ resid, float* __restrict__ out,
    int M, int N, int K, float scale, int relu) {
  __shared__ float As[64 * 128];
  __shared__ float Ws[128 * 64];
  int t = threadIdx.x;
  int ty = t >> 4, tx = t & 15;
  int row0 = blockIdx.x * 64, n0 = blockIdx.y * 64;
  float acc[4][4] = {};
  for (int kc = 0; kc < K; kc += 128) {
#pragma unroll
    for (int j = 0; j < 8; ++j) {
      int f = t + 256 * j;
      int r = f >> 5, c4 = f & 31;
      *(float4*)(As + r * 128 + c4 * 4) = *(const float4*)(A + (size_t)(row0 + r) * K + kc + c4 * 4);
    }
#pragma unroll
    for (int j = 0; j < 8; ++j) {
      int f = t + 256 * j;
      int kr = f >> 4, c4 = f & 15;
      *(float4*)(Ws + kr * 64 + c4 * 4) = *(const float4*)(W + (size_t)(kc + kr) * N + n0 + c4 * 4);
    }
    __syncthreads();
    for (int k0 = 0; k0 < 128; k0 += 4) {
      float a[4][4], b[4][4];
#pragma unroll
      for (int i = 0; i < 4; ++i) {
        float4 t4 = *(const float4*)(As + (4 * ty + i) * 128 + k0);
        a[i][0] = t4.x; a[i][1] = t4.y; a[i][2] = t4.z; a[i][3] = t4.w;
      }
#pragma unroll
      for (int kk = 0; kk < 4; ++kk) {
        float4 t4 = *(const float4*)(Ws + (k0 + kk) * 64 + 4 * tx);
        b[kk][0] = t4.x; b[kk][1] = t4.y; b[kk][2] = t4.z; b[kk][3] = t4.w;
      }
#pragma unroll
      for (int kk = 0; kk < 4; ++kk)
#pragma unroll
        for (int i = 0; i < 4; ++i)
#pragma unroll
          for (int j = 0; j < 4; ++j)
            acc[i][j] += a[i][kk] * b[kk][j];
    }
    __syncthreads();
  }
  float4 bv = make_float4(0.f, 0.f, 0.f, 0.f);
  if (bias) bv = *(const float4*)(bias + n0 + 4 * tx);
#pragma unroll
  for (int i = 0; i < 4; ++i) {
    float4 r;
    r.x = (acc[i][0] + bv.x) * scale;
    r.y = (acc[i][1] + bv.y) * scale;
    r.z = (acc[i][2] + bv.z) * scale;
    r.w = (acc[i][3] + bv.w) * scale;
    if (relu) { r.x = fmaxf(r.x, 0.f); r.y = fmaxf(r.y, 0.f); r.z = fmaxf(r.z, 0.f); r.w = fmaxf(r.w, 0.f); }
    size_t o = (size_t)(row0 + 4 * ty + i) * N + n0 + 4 * tx;
    if (resid) {
      float4 rv = *(const float4*)(resid + o);
      r.x += rv.x; r.y += rv.y; r.z += rv.z; r.w += rv.w;
    }
    *(float4*)(out + o) = r;
  }
}

// ---------------- flash attention (fp32, online softmax) ----------------
// grid 256 (= 16 b x 16 q-tiles of 32), block 256: thread = (q = t>>3 in tile, h = t&7).
// Never materializes scores; bias read streamed with register double-buffer prefetch.
__global__ __launch_bounds__(256) void attn_k(const float* __restrict__ Q, const float* __restrict__ K,
    const float* __restrict__ V, const float* __restrict__ bias, float* __restrict__ out) {
  __shared__ float Ks[64 * 128];
  __shared__ float Vs[64 * 128];
  const int t = threadIdx.x;
  const int b = blockIdx.x >> 4;
  const int qt = blockIdx.x & 15;
  const int q = t >> 3;
  const int h = t & 7;
  const int node = b * 512 + qt * 32 + q;

  float qf[16];
  {
    const float4* qp = (const float4*)(Q + (size_t)node * CC + h * 16);
    float4 q0 = qp[0], q1 = qp[1], q2 = qp[2], q3 = qp[3];
    qf[0] = q0.x; qf[1] = q0.y; qf[2] = q0.z; qf[3] = q0.w;
    qf[4] = q1.x; qf[5] = q1.y; qf[6] = q1.z; qf[7] = q1.w;
    qf[8] = q2.x; qf[9] = q2.y; qf[10] = q2.z; qf[11] = q2.w;
    qf[12] = q3.x; qf[13] = q3.y; qf[14] = q3.z; qf[15] = q3.w;
  }
  float m = -INFINITY, l = 0.f;
  float acc[16];
#pragma unroll
  for (int d = 0; d < 16; ++d) acc[d] = 0.f;

  const float* brow = bias + (size_t)node * 4096 + h;  // [B,N,N,H]: +k*8 steps over keys
  float bb_cur[8], bb_nxt[8];
#pragma unroll
  for (int j = 0; j < 8; ++j) bb_cur[j] = brow[j * 8];
#pragma unroll
  for (int j = 0; j < 8; ++j) bb_nxt[j] = 0.f;

  const size_t kbase = (size_t)b * 512 * CC;
  for (int kt = 0; kt < 8; ++kt) {
    __syncthreads();
#pragma unroll
    for (int j = 0; j < 8; ++j) {
      int f = t + 256 * j;
      int r = f >> 5, c4 = f & 31;
      *(float4*)(Ks + r * 128 + c4 * 4) = *(const float4*)(K + kbase + (size_t)(kt * 64 + r) * CC + c4 * 4);
      *(float4*)(Vs + r * 128 + c4 * 4) = *(const float4*)(V + kbase + (size_t)(kt * 64 + r) * CC + c4 * 4);
    }
    __syncthreads();
    for (int c = 0; c < 8; ++c) {
      int gc = kt * 8 + c;
      if (gc < 63) {
#pragma unroll
        for (int j = 0; j < 8; ++j) bb_nxt[j] = brow[(size_t)((gc + 1) * 8 + j) * 8];
      }
#pragma unroll
      for (int j = 0; j < 8; ++j) {
        int kk = c * 8 + j;
        const float4* kf = (const float4*)(Ks + kk * 128 + h * 16);
        float4 k0 = kf[0], k1 = kf[1], k2 = kf[2], k3 = kf[3];
        float s = bb_cur[j]
          + qf[0] * k0.x + qf[1] * k0.y + qf[2] * k0.z + qf[3] * k0.w
          + qf[4] * k1.x + qf[5] * k1.y + qf[6] * k1.z + qf[7] * k1.w
          + qf[8] * k2.x + qf[9] * k2.y + qf[10] * k2.z + qf[11] * k2.w
          + qf[12] * k3.x + qf[13] * k3.y + qf[14] * k3.z + qf[15] * k3.w;
        if (s > m) {
          float al = __expf(m - s);  // m=-inf first iter -> 0
          l *= al;
#pragma unroll
          for (int d = 0; d < 16; ++d) acc[d] *= al;
          m = s;
        }
        float p = __expf(s - m);
        l += p;
        const float4* vf = (const float4*)(Vs + kk * 128 + h * 16);
        float4 v0 = vf[0], v1 = vf[1], v2 = vf[2], v3 = vf[3];
        acc[0] += p * v0.x; acc[1] += p * v0.y; acc[2] += p * v0.z; acc[3] += p * v0.w;
        acc[4] += p * v1.x; acc[5] += p * v1.y; acc[6] += p * v1.z; acc[7] += p * v1.w;
        acc[8] += p * v2.x; acc[9] += p * v2.y; acc[10] += p * v2.z; acc[11] += p * v2.w;
        acc[12] += p * v3.x; acc[13] += p * v3.y; acc[14] += p * v3.z; acc[15] += p * v3.w;
      }
#pragma unroll
      for (int j = 0; j < 8; ++j) bb_cur[j] = bb_nxt[j];
    }
  }
  float inv = 1.f / l;
  float* op = out + (size_t)node * CC + h * 16;
  *(float4*)(op + 0)  = make_float4(acc[0] * inv, acc[1] * inv, acc[2] * inv, acc[3] * inv);
  *(float4*)(op + 4)  = make_float4(acc[4] * inv, acc[5] * inv, acc[6] * inv, acc[7] * inv);
  *(float4*)(op + 8)  = make_float4(acc[8] * inv, acc[9] * inv, acc[10] * inv, acc[11] * inv);
  *(float4*)(op + 12) = make_float4(acc[12] * inv, acc[13] * inv, acc[14] * inv, acc[15] * inv);
}

// ---------------- launcher ----------------

extern "C" void kernel_launch(void* const* d_in, const int* in_sizes, int n_in,
                              void* d_out, int out_size, void* d_ws, size_t ws_size,
                              hipStream_t stream) {
  const float* x      = (const float*)d_in[0];
  const int*   ei     = (const int*)d_in[1];   // [2,E]: src=ei, dst=ei+E
  const float* bias   = (const float*)d_in[3]; // batch (d_in[2]) unused: graphs equal-sized & sorted
  const float* conv_w = (const float*)d_in[4];
  const float* conv_b = (const float*)d_in[5];
  const float* wq = (const float*)d_in[6];
  const float* bq = (const float*)d_in[7];
  const float* wk = (const float*)d_in[8];
  const float* bk = (const float*)d_in[9];
  const float* wv = (const float*)d_in[10];
  const float* bv = (const float*)d_in[11];
  const float* wo = (const float*)d_in[12];
  const float* bo = (const float*)d_in[13];
  const float* w1 = (const float*)d_in[14];
  const float* b1 = (const float*)d_in[15];
  const float* w2 = (const float*)d_in[16];
  const float* b2 = (const float*)d_in[17];
  const float* g1 = (const float*)d_in[18];
  const float* be1 = (const float*)d_in[19];
  const float* g2 = (const float*)d_in[20];
  const float* be2 = (const float*)d_in[21];
  const float* g3 = (const float*)d_in[22];
  const float* be3 = (const float*)d_in[23];
  int E = in_sizes[1] / 2;

  float* ws = (float*)d_ws;
  const size_t NC = (size_t)NN * CC;
  float* xw     = ws;            // also reused as attention output
  float* h1pre  = ws + NC;       // hconv accumulator, then pre-BN branch1
  float* qb     = ws + 2 * NC;
  float* kb     = ws + 3 * NC;
  float* vb     = ws + 4 * NC;
  float* h2pre  = ws + 5 * NC;
  float* outbuf = ws + 6 * NC;
  float* hid    = ws + 2 * NC;   // reuse qb+kb (dead after attention) — 2M floats
  float* h3pre  = ws + 4 * NC;   // reuse vb (dead after attention)
  float* deg    = ws + 7 * NC;   // 8192 (becomes dinv in place)
  float* st     = ws + 7 * NC + NN;  // 1536 floats of BN stats/params

  hipMemsetAsync(h1pre, 0, NC * sizeof(float), stream);
  hipMemsetAsync(st, 0, 1536 * sizeof(float), stream);

  // ---- GCN branch
  fill_ones_k<<<NN / 256, 256, 0, stream>>>(deg, NN);
  count_deg_k<<<(E + 255) / 256, 256, 0, stream>>>(ei + E, deg, E);
  rsqrt_k<<<NN / 256, 256, 0, stream>>>(deg, NN);  // deg -> dinv in place
  gemm_k<<<dim3(NN / 64, 2), 256, 0, stream>>>(x, conv_w, nullptr, nullptr, xw, NN, CC, CC, 1.f, 0);
  scatter_k<<<(E * 32) / 256, 256, 0, stream>>>(ei, ei + E, xw, deg, h1pre, E);
  conv_finish_k<<<NC / 256, 256, 0, stream>>>(h1pre, xw, deg, conv_b, x);
  bn_stats_k<<<NN / 64, 256, 0, stream>>>(h1pre, st + 0, st + 128);

  // ---- attention branch
  gemm_k<<<dim3(NN / 64, 2), 256, 0, stream>>>(x, wq, bq, nullptr, qb, NN, CC, CC, 0.25f, 0); // *dh^-0.5
  gemm_k<<<dim3(NN / 64, 2), 256, 0, stream>>>(x, wk, bk, nullptr, kb, NN, CC, CC, 1.f, 0);
  gemm_k<<<dim3(NN / 64, 2), 256, 0, stream>>>(x, wv, bv, nullptr, vb, NN, CC, CC, 1.f, 0);
  attn_k<<<256, 256, 0, stream>>>(qb, kb, vb, bias, xw);  // att -> xw buffer
  gemm_k<<<dim3(NN / 64, 2), 256, 0, stream>>>(xw, wo, bo, x, h2pre, NN, CC, CC, 1.f, 0);
  bn_stats_k<<<NN / 64, 256, 0, stream>>>(h2pre, st + 256, st + 384);

  // ---- combine + MLP
  bn_finalize_k<<<1, 128, 0, stream>>>(st + 0, st + 128, g1, be1, st + 768, st + 896);
  bn_finalize_k<<<1, 128, 0, stream>>>(st + 256, st + 384, g2, be2, st + 1024, st + 1152);
  combine_k<<<NC / 256, 256, 0, stream>>>(h1pre, h2pre, st + 768, st + 896, st + 1024, st + 1152, outbuf);
  gemm_k<<<dim3(NN / 64, 4), 256, 0, stream>>>(outbuf, w1, b1, nullptr, hid, NN, 2 * CC, CC, 1.f, 1);
  gemm_k<<<dim3(NN / 64, 2), 256, 0, stream>>>(hid, w2, b2, outbuf, h3pre, NN, CC, 2 * CC, 1.f, 0);
  bn_stats_k<<<NN / 64, 256, 0, stream>>>(h3pre, st + 512, st + 640);
  bn_finalize_k<<<1, 128, 0, stream>>>(st + 512, st + 640, g3, be3, st + 1280, st + 1408);
  bn_apply_k<<<NC / 256, 256, 0, stream>>>(h3pre, st + 1280, st + 1408, (float*)d_out);
}

// Round 2
// 446.332 us; speedup vs baseline: 1.4364x; 1.4364x over previous
//
#include <hip/hip_runtime.h>
#include <cstddef>

#define NN 8192
#define CC 128

// ---------------- CSR build ----------------

__global__ __launch_bounds__(256) void count_deg_int_k(const int* __restrict__ dst, int* degi, int E) {
  int i = blockIdx.x * 256 + threadIdx.x;
  if (i < E) atomicAdd(&degi[dst[i]], 1);
}

__global__ __launch_bounds__(256) void dinv_k(const int* __restrict__ degi, float* __restrict__ dinv, int n) {
  int i = blockIdx.x * 256 + threadIdx.x;
  if (i < n) dinv[i] = rsqrtf((float)(degi[i] + 1));  // +1 self loop; always >= 1
}

// single-workgroup exclusive scan of 8192 ints -> rowstart[8193], cursor[8192]
__global__ __launch_bounds__(256) void scan_k(const int* __restrict__ degi, int* __restrict__ rowstart,
                                              int* __restrict__ cursor) {
  __shared__ int partial[256];
  int t = threadIdx.x;
  int base = t * 32;
  int local[32];
  int s = 0;
#pragma unroll
  for (int i = 0; i < 32; ++i) { local[i] = s; s += degi[base + i]; }
  partial[t] = s;
  __syncthreads();
  for (int off = 1; off < 256; off <<= 1) {
    int v = (t >= off) ? partial[t - off] : 0;
    __syncthreads();
    partial[t] += v;
    __syncthreads();
  }
  int offset = partial[t] - s;  // exclusive
#pragma unroll
  for (int i = 0; i < 32; ++i) {
    rowstart[base + i] = offset + local[i];
    cursor[base + i] = offset + local[i];
  }
  if (t == 255) rowstart[NN] = offset + s;
}

__global__ __launch_bounds__(256) void bucket_k(const int* __restrict__ src, const int* __restrict__ dst,
    int* __restrict__ cursor, int* __restrict__ col, int E) {
  int e = blockIdx.x * 256 + threadIdx.x;
  if (e >= E) return;
  int d = dst[e];
  int pos = atomicAdd(&cursor[d], 1);
  col[pos] = src[e];
}

// h1 = sum_in-edges xw[s]*dinv[s]*dinv[d] + xw[d]*dinv[d]^2 + conv_b + x   (pre-BN branch 1)
// block 256 = 2 nodes x 128 channels
__global__ __launch_bounds__(256) void gather_k(const int* __restrict__ rowstart, const int* __restrict__ col,
    const float* __restrict__ xw, const float* __restrict__ dinv, const float* __restrict__ cb,
    const float* __restrict__ x, float* __restrict__ h1) {
  int d = blockIdx.x * 2 + (threadIdx.x >> 7);
  int c = threadIdx.x & 127;
  int j0 = rowstart[d], j1 = rowstart[d + 1];
  float dd = dinv[d];
  float sum = 0.f;
  int s_next = (j0 < j1) ? col[j0] : 0;
  for (int j = j0; j < j1; ++j) {
    int s = s_next;
    if (j + 1 < j1) s_next = col[j + 1];
    sum += xw[(size_t)s * CC + c] * dinv[s];
  }
  sum *= dd;
  int idx = d * CC + c;
  sum += xw[idx] * dd * dd;      // self loop
  h1[idx] = sum + cb[c] + x[idx];
}

// ---------------- BN helpers ----------------

__global__ __launch_bounds__(256) void bn_stats_k(const float* __restrict__ X,
    float* __restrict__ sums, float* __restrict__ sumsq) {
  int t = threadIdx.x;
  int c = t & 127, rg = t >> 7;
  int r0 = blockIdx.x * 64;
  float s = 0.f, sq = 0.f;
  for (int i = 0; i < 32; ++i) {
    float v = X[(size_t)(r0 + rg + 2 * i) * CC + c];
    s += v; sq += v * v;
  }
  atomicAdd(&sums[c], s);
  atomicAdd(&sumsq[c], sq);
}

__global__ void bn_finalize_k(const float* sums, const float* sumsq, const float* g, const float* be,
                              float* scale, float* shift) {
  int c = threadIdx.x;
  float mu = sums[c] * (1.0f / NN);
  float var = sumsq[c] * (1.0f / NN) - mu * mu;   // biased var, matches reference
  float sc = g[c] * rsqrtf(var + 1e-5f);
  scale[c] = sc;
  shift[c] = be[c] - mu * sc;
}

__global__ __launch_bounds__(256) void combine_k(const float* __restrict__ h1, const float* __restrict__ h2,
    const float* __restrict__ sc0, const float* __restrict__ sh0,
    const float* __restrict__ sc1, const float* __restrict__ sh1, float* __restrict__ out) {
  int idx = blockIdx.x * 256 + threadIdx.x;
  int c = idx & 127;
  out[idx] = sc0[c] * h1[idx] + sh0[c] + sc1[c] * h2[idx] + sh1[c];
}

__global__ __launch_bounds__(256) void bn_apply_k(const float* __restrict__ h, const float* __restrict__ sc,
    const float* __restrict__ sh, float* __restrict__ out) {
  int idx = blockIdx.x * 256 + threadIdx.x;
  int c = idx & 127;
  out[idx] = sc[c] * h[idx] + sh[c];
}

// ---------------- fp32 GEMM: out = (A@W + bias)*scale, optional relu, + resid ----------------
// grid (M/64, N/64), block 256. 64x64 tile, 4x4 register tile per thread.
__global__ __launch_bounds__(256) void gemm_k(const float* __restrict__ A, const float* __restrict__ W,
    const float* __restrict__ bias, const float* __restrict__ resid, float* __restrict__ out,
    int M, int N, int K, float scale, int relu) {
  __shared__ float As[64 * 128];
  __shared__ float Ws[128 * 64];
  int t = threadIdx.x;
  int ty = t >> 4, tx = t & 15;
  int row0 = blockIdx.x * 64, n0 = blockIdx.y * 64;
  float acc[4][4] = {};
  for (int kc = 0; kc < K; kc += 128) {
#pragma unroll
    for (int j = 0; j < 8; ++j) {
      int f = t + 256 * j;
      int r = f >> 5, c4 = f & 31;
      *(float4*)(As + r * 128 + c4 * 4) = *(const float4*)(A + (size_t)(row0 + r) * K + kc + c4 * 4);
    }
#pragma unroll
    for (int j = 0; j < 8; ++j) {
      int f = t + 256 * j;
      int kr = f >> 4, c4 = f & 15;
      *(float4*)(Ws + kr * 64 + c4 * 4) = *(const float4*)(W + (size_t)(kc + kr) * N + n0 + c4 * 4);
    }
    __syncthreads();
    for (int k0 = 0; k0 < 128; k0 += 4) {
      float a[4][4], b[4][4];
#pragma unroll
      for (int i = 0; i < 4; ++i) {
        float4 t4 = *(const float4*)(As + (4 * ty + i) * 128 + k0);
        a[i][0] = t4.x; a[i][1] = t4.y; a[i][2] = t4.z; a[i][3] = t4.w;
      }
#pragma unroll
      for (int kk = 0; kk < 4; ++kk) {
        float4 t4 = *(const float4*)(Ws + (k0 + kk) * 64 + 4 * tx);
        b[kk][0] = t4.x; b[kk][1] = t4.y; b[kk][2] = t4.z; b[kk][3] = t4.w;
      }
#pragma unroll
      for (int kk = 0; kk < 4; ++kk)
#pragma unroll
        for (int i = 0; i < 4; ++i)
#pragma unroll
          for (int j = 0; j < 4; ++j)
            acc[i][j] += a[i][kk] * b[kk][j];
    }
    __syncthreads();
  }
  float4 bv = make_float4(0.f, 0.f, 0.f, 0.f);
  if (bias) bv = *(const float4*)(bias + n0 + 4 * tx);
#pragma unroll
  for (int i = 0; i < 4; ++i) {
    float4 r;
    r.x = (acc[i][0] + bv.x) * scale;
    r.y = (acc[i][1] + bv.y) * scale;
    r.z = (acc[i][2] + bv.z) * scale;
    r.w = (acc[i][3] + bv.w) * scale;
    if (relu) { r.x = fmaxf(r.x, 0.f); r.y = fmaxf(r.y, 0.f); r.z = fmaxf(r.z, 0.f); r.w = fmaxf(r.w, 0.f); }
    size_t o = (size_t)(row0 + 4 * ty + i) * N + n0 + 4 * tx;
    if (resid) {
      float4 rv = *(const float4*)(resid + o);
      r.x += rv.x; r.y += rv.y; r.z += rv.z; r.w += rv.w;
    }
    *(float4*)(out + o) = r;
  }
}

// ---------------- flash attention (fp32, online softmax) ----------------
// grid 256 (= 16 b x 16 q-tiles of 32), block 256: thread = (q = t>>3 in tile, h = t&7).
__global__ __launch_bounds__(256) void attn_k(const float* __restrict__ Q, const float* __restrict__ K,
    const float* __restrict__ V, const float* __restrict__ bias, float* __restrict__ out) {
  __shared__ float Ks[64 * 128];
  __shared__ float Vs[64 * 128];
  const int t = threadIdx.x;
  const int b = blockIdx.x >> 4;
  const int qt = blockIdx.x & 15;
  const int q = t >> 3;
  const int h = t & 7;
  const int node = b * 512 + qt * 32 + q;

  float qf[16];
  {
    const float4* qp = (const float4*)(Q + (size_t)node * CC + h * 16);
    float4 q0 = qp[0], q1 = qp[1], q2 = qp[2], q3 = qp[3];
    qf[0] = q0.x; qf[1] = q0.y; qf[2] = q0.z; qf[3] = q0.w;
    qf[4] = q1.x; qf[5] = q1.y; qf[6] = q1.z; qf[7] = q1.w;
    qf[8] = q2.x; qf[9] = q2.y; qf[10] = q2.z; qf[11] = q2.w;
    qf[12] = q3.x; qf[13] = q3.y; qf[14] = q3.z; qf[15] = q3.w;
  }
  float m = -INFINITY, l = 0.f;
  float acc[16];
#pragma unroll
  for (int d = 0; d < 16; ++d) acc[d] = 0.f;

  const float* brow = bias + (size_t)node * 4096 + h;  // [B,N,N,H]: +k*8 steps over keys
  float bb_cur[8], bb_nxt[8];
#pragma unroll
  for (int j = 0; j < 8; ++j) bb_cur[j] = brow[j * 8];
#pragma unroll
  for (int j = 0; j < 8; ++j) bb_nxt[j] = 0.f;

  const size_t kbase = (size_t)b * 512 * CC;
  for (int kt = 0; kt < 8; ++kt) {
    __syncthreads();
#pragma unroll
    for (int j = 0; j < 8; ++j) {
      int f = t + 256 * j;
      int r = f >> 5, c4 = f & 31;
      *(float4*)(Ks + r * 128 + c4 * 4) = *(const float4*)(K + kbase + (size_t)(kt * 64 + r) * CC + c4 * 4);
      *(float4*)(Vs + r * 128 + c4 * 4) = *(const float4*)(V + kbase + (size_t)(kt * 64 + r) * CC + c4 * 4);
    }
    __syncthreads();
    for (int c = 0; c < 8; ++c) {
      int gc = kt * 8 + c;
      if (gc < 63) {
#pragma unroll
        for (int j = 0; j < 8; ++j) bb_nxt[j] = brow[(size_t)((gc + 1) * 8 + j) * 8];
      }
#pragma unroll
      for (int j = 0; j < 8; ++j) {
        int kk = c * 8 + j;
        const float4* kf = (const float4*)(Ks + kk * 128 + h * 16);
        float4 k0 = kf[0], k1 = kf[1], k2 = kf[2], k3 = kf[3];
        float s = bb_cur[j]
          + qf[0] * k0.x + qf[1] * k0.y + qf[2] * k0.z + qf[3] * k0.w
          + qf[4] * k1.x + qf[5] * k1.y + qf[6] * k1.z + qf[7] * k1.w
          + qf[8] * k2.x + qf[9] * k2.y + qf[10] * k2.z + qf[11] * k2.w
          + qf[12] * k3.x + qf[13] * k3.y + qf[14] * k3.z + qf[15] * k3.w;
        if (s > m) {
          float al = __expf(m - s);  // m=-inf first iter -> 0
          l *= al;
#pragma unroll
          for (int d = 0; d < 16; ++d) acc[d] *= al;
          m = s;
        }
        float p = __expf(s - m);
        l += p;
        const float4* vf = (const float4*)(Vs + kk * 128 + h * 16);
        float4 v0 = vf[0], v1 = vf[1], v2 = vf[2], v3 = vf[3];
        acc[0] += p * v0.x; acc[1] += p * v0.y; acc[2] += p * v0.z; acc[3] += p * v0.w;
        acc[4] += p * v1.x; acc[5] += p * v1.y; acc[6] += p * v1.z; acc[7] += p * v1.w;
        acc[8] += p * v2.x; acc[9] += p * v2.y; acc[10] += p * v2.z; acc[11] += p * v2.w;
        acc[12] += p * v3.x; acc[13] += p * v3.y; acc[14] += p * v3.z; acc[15] += p * v3.w;
      }
#pragma unroll
      for (int j = 0; j < 8; ++j) bb_cur[j] = bb_nxt[j];
    }
  }
  float inv = 1.f / l;
  float* op = out + (size_t)node * CC + h * 16;
  *(float4*)(op + 0)  = make_float4(acc[0] * inv, acc[1] * inv, acc[2] * inv, acc[3] * inv);
  *(float4*)(op + 4)  = make_float4(acc[4] * inv, acc[5] * inv, acc[6] * inv, acc[7] * inv);
  *(float4*)(op + 8)  = make_float4(acc[8] * inv, acc[9] * inv, acc[10] * inv, acc[11] * inv);
  *(float4*)(op + 12) = make_float4(acc[12] * inv, acc[13] * inv, acc[14] * inv, acc[15] * inv);
}

// ---------------- launcher ----------------

extern "C" void kernel_launch(void* const* d_in, const int* in_sizes, int n_in,
                              void* d_out, int out_size, void* d_ws, size_t ws_size,
                              hipStream_t stream) {
  const float* x      = (const float*)d_in[0];
  const int*   ei     = (const int*)d_in[1];   // [2,E]: src=ei, dst=ei+E
  const float* bias   = (const float*)d_in[3]; // batch (d_in[2]) unused: graphs equal-sized & sorted
  const float* conv_w = (const float*)d_in[4];
  const float* conv_b = (const float*)d_in[5];
  const float* wq = (const float*)d_in[6];
  const float* bq = (const float*)d_in[7];
  const float* wk = (const float*)d_in[8];
  const float* bk = (const float*)d_in[9];
  const float* wv = (const float*)d_in[10];
  const float* bv = (const float*)d_in[11];
  const float* wo = (const float*)d_in[12];
  const float* bo = (const float*)d_in[13];
  const float* w1 = (const float*)d_in[14];
  const float* b1 = (const float*)d_in[15];
  const float* w2 = (const float*)d_in[16];
  const float* b2 = (const float*)d_in[17];
  const float* g1 = (const float*)d_in[18];
  const float* be1 = (const float*)d_in[19];
  const float* g2 = (const float*)d_in[20];
  const float* be2 = (const float*)d_in[21];
  const float* g3 = (const float*)d_in[22];
  const float* be3 = (const float*)d_in[23];
  int E = in_sizes[1] / 2;

  float* ws = (float*)d_ws;
  const size_t NC = (size_t)NN * CC;
  float* xw     = ws;            // also reused as attention output
  float* h1pre  = ws + NC;
  float* qb     = ws + 2 * NC;
  float* kb     = ws + 3 * NC;
  float* vb     = ws + 4 * NC;
  float* h2pre  = ws + 5 * NC;
  float* outbuf = ws + 6 * NC;
  float* hid    = ws + 2 * NC;   // reuse qb+kb (dead after attention) — 2M floats
  float* h3pre  = ws + 4 * NC;   // reuse vb (dead after attention)
  float* st     = ws + 7 * NC;   // 1536 floats of BN stats/params
  float* dinv   = ws + 7 * NC + 1536;            // 8192 floats
  int*   degi     = (int*)(ws + 7 * NC + 1536 + NN);  // 8192
  int*   rowstart = degi + NN;                        // 8193
  int*   cursor   = rowstart + NN + 1;                // 8192
  int*   col      = cursor + NN;                      // E

  hipMemsetAsync(degi, 0, NN * sizeof(int), stream);
  hipMemsetAsync(st, 0, 1536 * sizeof(float), stream);

  // ---- GCN branch: CSR build + gather (no big-array atomics)
  count_deg_int_k<<<(E + 255) / 256, 256, 0, stream>>>(ei + E, degi, E);
  dinv_k<<<NN / 256, 256, 0, stream>>>(degi, dinv, NN);
  scan_k<<<1, 256, 0, stream>>>(degi, rowstart, cursor);
  bucket_k<<<(E + 255) / 256, 256, 0, stream>>>(ei, ei + E, cursor, col, E);
  gemm_k<<<dim3(NN / 64, 2), 256, 0, stream>>>(x, conv_w, nullptr, nullptr, xw, NN, CC, CC, 1.f, 0);
  gather_k<<<NN / 2, 256, 0, stream>>>(rowstart, col, xw, dinv, conv_b, x, h1pre);
  bn_stats_k<<<NN / 64, 256, 0, stream>>>(h1pre, st + 0, st + 128);

  // ---- attention branch
  gemm_k<<<dim3(NN / 64, 2), 256, 0, stream>>>(x, wq, bq, nullptr, qb, NN, CC, CC, 0.25f, 0); // *dh^-0.5
  gemm_k<<<dim3(NN / 64, 2), 256, 0, stream>>>(x, wk, bk, nullptr, kb, NN, CC, CC, 1.f, 0);
  gemm_k<<<dim3(NN / 64, 2), 256, 0, stream>>>(x, wv, bv, nullptr, vb, NN, CC, CC, 1.f, 0);
  attn_k<<<256, 256, 0, stream>>>(qb, kb, vb, bias, xw);  // att -> xw buffer
  gemm_k<<<dim3(NN / 64, 2), 256, 0, stream>>>(xw, wo, bo, x, h2pre, NN, CC, CC, 1.f, 0);
  bn_stats_k<<<NN / 64, 256, 0, stream>>>(h2pre, st + 256, st + 384);

  // ---- combine + MLP
  bn_finalize_k<<<1, 128, 0, stream>>>(st + 0, st + 128, g1, be1, st + 768, st + 896);
  bn_finalize_k<<<1, 128, 0, stream>>>(st + 256, st + 384, g2, be2, st + 1024, st + 1152);
  combine_k<<<NC / 256, 256, 0, stream>>>(h1pre, h2pre, st + 768, st + 896, st + 1024, st + 1152, outbuf);
  gemm_k<<<dim3(NN / 64, 4), 256, 0, stream>>>(outbuf, w1, b1, nullptr, hid, NN, 2 * CC, CC, 1.f, 1);
  gemm_k<<<dim3(NN / 64, 2), 256, 0, stream>>>(hid, w2, b2, outbuf, h3pre, NN, CC, 2 * CC, 1.f, 0);
  bn_stats_k<<<NN / 64, 256, 0, stream>>>(h3pre, st + 512, st + 640);
  bn_finalize_k<<<1, 128, 0, stream>>>(st + 512, st + 640, g3, be3, st + 1280, st + 1408);
  bn_apply_k<<<NC / 256, 256, 0, stream>>>(h3pre, st + 1280, st + 1408, (float*)d_out);
}